// Round 9
// baseline (731.936 us; speedup 1.0000x reference)
//
#include <hip/hip_runtime.h>
#include <math.h>

#define kD 2048
#define kH 32
#define kN 64
#define kS 2048

typedef unsigned short ushort_t;
typedef unsigned int uint32;

__device__ __forceinline__ ushort_t f2bf(float f) {
  uint32 u = __float_as_uint(f);
  u += 0x7fffu + ((u >> 16) & 1u);   // RNE
  return (ushort_t)(u >> 16);
}
__device__ __forceinline__ float bf2f(ushort_t u) {
  return __uint_as_float(((uint32)u) << 16);
}
__device__ __forceinline__ float sigm(float x) { return 1.f / (1.f + __expf(-x)); }

// ---------------- LayerNorm (ln1): vectorized (8 elem/thread) ----------------
__global__ __launch_bounds__(256) void ln1_kernel(
    const float* __restrict__ x, const float* __restrict__ w, const float* __restrict__ b,
    ushort_t* __restrict__ xnbf, ushort_t* __restrict__ xprevbf,
    const float* __restrict__ state1, float* __restrict__ state1_out)
{
  int t = blockIdx.x;
  const float* row = x + (size_t)t * kD;
  int d0 = threadIdx.x * 8;
  float4 v0 = *(const float4*)(row + d0);
  float4 v1 = *(const float4*)(row + d0 + 4);
  float vv[8] = { v0.x, v0.y, v0.z, v0.w, v1.x, v1.y, v1.z, v1.w };
  float s = 0.f, s2 = 0.f;
  #pragma unroll
  for (int j = 0; j < 8; j++) { s += vv[j]; s2 += vv[j] * vv[j]; }
  #pragma unroll
  for (int o = 32; o > 0; o >>= 1) { s += __shfl_down(s, o); s2 += __shfl_down(s2, o); }
  __shared__ float ls[4], ls2[4];
  int wid = threadIdx.x >> 6;
  if ((threadIdx.x & 63) == 0) { ls[wid] = s; ls2[wid] = s2; }
  __syncthreads();
  s = ls[0] + ls[1] + ls[2] + ls[3];
  s2 = ls2[0] + ls2[1] + ls2[2] + ls2[3];
  float mean = s * (1.f / kD);
  float var = s2 * (1.f / kD) - mean * mean;
  float rstd = rsqrtf(var + 1e-5f);
  float4 w0 = *(const float4*)(w + d0), w1 = *(const float4*)(w + d0 + 4);
  float4 b0 = *(const float4*)(b + d0), b1 = *(const float4*)(b + d0 + 4);
  float ww[8] = { w0.x, w0.y, w0.z, w0.w, w1.x, w1.y, w1.z, w1.w };
  float bb[8] = { b0.x, b0.y, b0.z, b0.w, b1.x, b1.y, b1.z, b1.w };
  float o8[8];
  ushort_t ob[8];
  #pragma unroll
  for (int j = 0; j < 8; j++) {
    o8[j] = (vv[j] - mean) * rstd * ww[j] + bb[j];
    ob[j] = f2bf(o8[j]);
  }
  *(uint4*)(xnbf + (size_t)t * kD + d0) = *(const uint4*)ob;
  if (t < kS - 1) {
    *(uint4*)(xprevbf + (size_t)(t + 1) * kD + d0) = *(const uint4*)ob;
  } else {
    *(float4*)(state1_out + d0)     = make_float4(o8[0], o8[1], o8[2], o8[3]);
    *(float4*)(state1_out + d0 + 4) = make_float4(o8[4], o8[5], o8[6], o8[7]);
  }
  if (t == 0) {
    float4 s0 = *(const float4*)(state1 + d0);
    float4 s1 = *(const float4*)(state1 + d0 + 4);
    float sv[8] = { s0.x, s0.y, s0.z, s0.w, s1.x, s1.y, s1.z, s1.w };
    ushort_t sb[8];
    #pragma unroll
    for (int j = 0; j < 8; j++) sb[j] = f2bf(sv[j]);
    *(uint4*)(xprevbf + d0) = *(const uint4*)sb;
  }
}

// ---------------- mix + bf16 convert, vectorized (8 elem/thread) -------------
__global__ __launch_bounds__(256) void mix3_cvt(
    const ushort_t* __restrict__ xnbf, const ushort_t* __restrict__ xprevbf,
    const float* __restrict__ cr, const float* __restrict__ ck, const float* __restrict__ cv,
    ushort_t* __restrict__ Ar, ushort_t* __restrict__ Ak, ushort_t* __restrict__ Av)
{
  int t = blockIdx.x;
  size_t base = (size_t)t * kD;
  int d0 = threadIdx.x * 8;
  uint4 xa = *(const uint4*)(xnbf + base + d0);
  uint4 xb = *(const uint4*)(xprevbf + base + d0);
  const ushort_t* pa = (const ushort_t*)&xa;
  const ushort_t* pb = (const ushort_t*)&xb;
  float c8[8], dx[8];
  #pragma unroll
  for (int j = 0; j < 8; j++) {
    c8[j] = bf2f(pa[j]);
    dx[j] = bf2f(pb[j]) - c8[j];
  }
  float4 r0 = *(const float4*)(cr + d0), r1 = *(const float4*)(cr + d0 + 4);
  float4 k0 = *(const float4*)(ck + d0), k1 = *(const float4*)(ck + d0 + 4);
  float4 v0 = *(const float4*)(cv + d0), v1 = *(const float4*)(cv + d0 + 4);
  float rr[8] = { r0.x, r0.y, r0.z, r0.w, r1.x, r1.y, r1.z, r1.w };
  float kk[8] = { k0.x, k0.y, k0.z, k0.w, k1.x, k1.y, k1.z, k1.w };
  float vv[8] = { v0.x, v0.y, v0.z, v0.w, v1.x, v1.y, v1.z, v1.w };
  ushort_t orr[8], okk[8], ovv[8];
  #pragma unroll
  for (int j = 0; j < 8; j++) {
    orr[j] = f2bf(c8[j] + dx[j] * rr[j]);
    okk[j] = f2bf(c8[j] + dx[j] * kk[j]);
    ovv[j] = f2bf(c8[j] + dx[j] * vv[j]);
  }
  *(uint4*)(Ar + base + d0) = *(const uint4*)orr;
  *(uint4*)(Ak + base + d0) = *(const uint4*)okk;
  *(uint4*)(Av + base + d0) = *(const uint4*)ovv;
}

// ---------------- batched fp32 -> bf16 ----------------
struct CvtArgs { const float* src[3]; ushort_t* dst[3]; };
__global__ __launch_bounds__(256) void cvt_bf16_b(CvtArgs args)
{
  const float* in = args.src[blockIdx.y];
  ushort_t* out = args.dst[blockIdx.y];
  int idx = blockIdx.x * 256 + threadIdx.x;
  float4 v = ((const float4*)in)[idx];
  ushort_t o[4] = { f2bf(v.x), f2bf(v.y), f2bf(v.z), f2bf(v.w) };
  ((uint2*)out)[idx] = *(const uint2*)o;
}

// ---------------- batched bf16 MFMA NT GEMM (128x128, BK=64) ----------------
typedef __bf16 bf16x8 __attribute__((ext_vector_type(8)));
typedef float f32x4 __attribute__((ext_vector_type(4)));

struct GemmArgs {
  const ushort_t* A[3];
  const ushort_t* B[3];
  float* C[3];
  const float* resid[3];
};

__global__ __launch_bounds__(256) void gemm_bf16_b(GemmArgs args)
{
  int z = blockIdx.z;
  const ushort_t* __restrict__ A = args.A[z];
  const ushort_t* __restrict__ B = args.B[z];
  float* __restrict__ C = args.C[z];
  const float* __restrict__ resid = args.resid[z];

  __shared__ __align__(16) ushort_t As[128 * 64];
  __shared__ __align__(16) ushort_t Bs[128 * 64];
  int tid = threadIdx.x;
  int w = tid >> 6, lane = tid & 63;
  int row0 = blockIdx.y * 128, col0 = blockIdx.x * 128;
  int wrow = (w >> 1) * 64, wcol = (w & 1) * 64;
  int quad = lane >> 4, r16 = lane & 15;
  f32x4 acc[4][4] = {};

  int lrow = lane >> 3;
  int lsw  = (lane & 7) ^ lrow;

  for (int k0 = 0; k0 < kD; k0 += 64) {
    #pragma unroll
    for (int n = 0; n < 4; n++) {
      int rr = w * 32 + n * 8 + lrow;
      int cc = k0 + lsw * 8;
      const ushort_t* ga = A + (size_t)(row0 + rr) * kD + cc;
      const ushort_t* gb = B + (size_t)(col0 + rr) * kD + cc;
      __builtin_amdgcn_global_load_lds(
          (const __attribute__((address_space(1))) uint32*)ga,
          (__attribute__((address_space(3))) uint32*)&As[(w * 32 + n * 8) * 64], 16, 0, 0);
      __builtin_amdgcn_global_load_lds(
          (const __attribute__((address_space(1))) uint32*)gb,
          (__attribute__((address_space(3))) uint32*)&Bs[(w * 32 + n * 8) * 64], 16, 0, 0);
    }
    __syncthreads();
    #pragma unroll
    for (int kk = 0; kk < 64; kk += 32) {
      bf16x8 af[4], bfr[4];
      #pragma unroll
      for (int i = 0; i < 4; i++) {
        int row = wrow + i * 16 + r16;
        int chunk = ((kk >> 3) + quad) ^ (r16 & 7);
        af[i] = *(const bf16x8*)&As[row * 64 + chunk * 8];
      }
      #pragma unroll
      for (int j = 0; j < 4; j++) {
        int row = wcol + j * 16 + r16;
        int chunk = ((kk >> 3) + quad) ^ (r16 & 7);
        bfr[j] = *(const bf16x8*)&Bs[row * 64 + chunk * 8];
      }
      #pragma unroll
      for (int i = 0; i < 4; i++)
        #pragma unroll
        for (int j = 0; j < 4; j++)
          acc[i][j] = __builtin_amdgcn_mfma_f32_16x16x32_bf16(af[i], bfr[j], acc[i][j], 0, 0, 0);
    }
    __syncthreads();
  }
  #pragma unroll
  for (int i = 0; i < 4; i++) {
    #pragma unroll
    for (int j = 0; j < 4; j++) {
      int col = col0 + wcol + j * 16 + r16;
      #pragma unroll
      for (int reg = 0; reg < 4; reg++) {
        int row = row0 + wrow + i * 16 + quad * 4 + reg;
        float v = acc[i][j][reg];
        if (resid) v += resid[(size_t)row * kD + col];
        C[(size_t)row * kD + col] = v;
      }
    }
  }
}

// ---------------- prep W1cat: B1[col][k] (320 x 4096 bf16) -------------------
struct PrepW1Args { const float* w1[4]; const float* c[4]; ushort_t* B1; };
__global__ __launch_bounds__(256) void prep_w1(PrepW1Args a)
{
  __shared__ float tile[64][17];
  int k0 = blockIdx.x * 64;
  int col0 = blockIdx.y * 16;
  int z, lc0, L;
  if (col0 < 128)      { z = 0; lc0 = col0;       L = 128; }
  else if (col0 < 192) { z = 1; lc0 = col0 - 128; L = 64; }
  else if (col0 < 256) { z = 2; lc0 = col0 - 192; L = 64; }
  else if (col0 < 288) { z = 3; lc0 = col0 - 256; L = 32; }
  else z = -1;
  int tid = threadIdx.x;
  if (z >= 0) {
    const float* W = a.w1[z];
    const float* C = a.c[z];
    int cc = tid & 15, kk = tid >> 4;
    #pragma unroll
    for (int i = 0; i < 4; i++) {
      int k = k0 + kk + i * 16;
      int ksrc = k & (kD - 1);
      float cv = C[ksrc];
      float sc = (k < kD) ? (1.f - cv) : cv;
      tile[kk + i * 16][cc] = W[(size_t)ksrc * L + lc0 + cc] * sc;
    }
  }
  __syncthreads();
  int kk2 = tid & 63, cc2 = tid >> 6;
  #pragma unroll
  for (int i = 0; i < 4; i++) {
    int col = col0 + cc2 * 4 + i;
    float v = (z >= 0) ? tile[kk2][cc2 * 4 + i] : 0.f;
    a.B1[(size_t)col * 4096 + k0 + kk2] = f2bf(v);
  }
}

// ---------------- prep W2: per-z transpose (L x 2048 -> 2048 x L bf16) -------
struct PrepW2Args { const float* w2[4]; ushort_t* B2[4]; int L[4]; };
__global__ __launch_bounds__(256) void prep_w2(PrepW2Args a)
{
  __shared__ float tile[64][17];
  int z = blockIdx.z;
  int L = a.L[z];
  int l0 = blockIdx.y * 16;
  if (l0 >= L) return;
  int j0 = blockIdx.x * 64;
  int tid = threadIdx.x;
  const float* W = a.w2[z];
  ushort_t* out = a.B2[z];
  int jj = tid & 63;
  #pragma unroll
  for (int i = 0; i < 4; i++) {
    int ll = (tid >> 6) * 4 + i;
    tile[jj][ll] = W[(size_t)(l0 + ll) * kD + j0 + jj];
  }
  __syncthreads();
  int ll2 = tid & 15;
  #pragma unroll
  for (int i = 0; i < 4; i++) {
    int jj2 = (tid >> 4) + i * 16;
    out[(size_t)(j0 + jj2) * L + l0 + ll2] = f2bf(tile[jj2][ll2]);
  }
}

// ---------------- GEMM1: H = [xn | xprev] @ B1cat^T  (2048 x 4096 x 320) -----
__global__ __launch_bounds__(256) void gemm1_kernel(
    const ushort_t* __restrict__ xnbf, const ushort_t* __restrict__ xprevbf,
    const ushort_t* __restrict__ B1, ushort_t* __restrict__ H)
{
  __shared__ __align__(16) ushort_t As[128 * 64];
  __shared__ __align__(16) ushort_t Bs[64 * 64];
  int tid = threadIdx.x;
  int w = tid >> 6, lane = tid & 63;
  int col0 = blockIdx.x * 64, row0 = blockIdx.y * 128;
  int quad = lane >> 4, r16 = lane & 15;
  f32x4 acc[2][4] = {};
  int lrow = lane >> 3;
  int lsw = (lane & 7) ^ lrow;

  for (int k0 = 0; k0 < 4096; k0 += 64) {
    const ushort_t* Abase = (k0 < kD) ? (xnbf + k0) : (xprevbf + (k0 - kD));
    #pragma unroll
    for (int n = 0; n < 4; n++) {
      int rr = w * 32 + n * 8 + lrow;
      const ushort_t* ga = Abase + (size_t)(row0 + rr) * kD + lsw * 8;
      __builtin_amdgcn_global_load_lds(
          (const __attribute__((address_space(1))) uint32*)ga,
          (__attribute__((address_space(3))) uint32*)&As[(w * 32 + n * 8) * 64], 16, 0, 0);
    }
    #pragma unroll
    for (int n = 0; n < 2; n++) {
      int rr = w * 16 + n * 8 + lrow;
      const ushort_t* gb = B1 + (size_t)(col0 + rr) * 4096 + k0 + lsw * 8;
      __builtin_amdgcn_global_load_lds(
          (const __attribute__((address_space(1))) uint32*)gb,
          (__attribute__((address_space(3))) uint32*)&Bs[(w * 16 + n * 8) * 64], 16, 0, 0);
    }
    __syncthreads();
    #pragma unroll
    for (int kk = 0; kk < 64; kk += 32) {
      bf16x8 af[2], bfr[4];
      #pragma unroll
      for (int i = 0; i < 2; i++) {
        int row = w * 32 + i * 16 + r16;
        int chunk = ((kk >> 3) + quad) ^ (r16 & 7);
        af[i] = *(const bf16x8*)&As[row * 64 + chunk * 8];
      }
      #pragma unroll
      for (int j = 0; j < 4; j++) {
        int row = j * 16 + r16;
        int chunk = ((kk >> 3) + quad) ^ (r16 & 7);
        bfr[j] = *(const bf16x8*)&Bs[row * 64 + chunk * 8];
      }
      #pragma unroll
      for (int i = 0; i < 2; i++)
        #pragma unroll
        for (int j = 0; j < 4; j++)
          acc[i][j] = __builtin_amdgcn_mfma_f32_16x16x32_bf16(af[i], bfr[j], acc[i][j], 0, 0, 0);
    }
    __syncthreads();
  }
  #pragma unroll
  for (int i = 0; i < 2; i++) {
    #pragma unroll
    for (int j = 0; j < 4; j++) {
      int col = col0 + j * 16 + r16;
      #pragma unroll
      for (int reg = 0; reg < 4; reg++) {
        int row = row0 + w * 32 + i * 16 + quad * 4 + reg;
        float v = acc[i][j][reg];
        if (col < 128) v = sigm(v);
        else if (col >= 192 && col < 256) v = tanhf(v);
        H[(size_t)row * 320 + col] = f2bf(v);
      }
    }
  }
}

// ---------------- GEMM2 (z-batched, K=Lz): out = act(H_z @ W2_z + bias) ------
struct Gemm2Args {
  const ushort_t* H;
  const ushort_t* B2[4];
  int Aofs[4];
  int L[4];
  const float* bias[4];
  float* out[4];
  const float* vfirst;
};
__global__ __launch_bounds__(256) void gemm2_kernel(Gemm2Args a)
{
  int z = blockIdx.z;
  int L = a.L[z];
  int nch = L >> 3;
  int rs = __builtin_ctz(nch);
  int mask = (nch >= 8) ? 7 : (nch - 1);
  __shared__ __align__(16) ushort_t As[128 * 128];
  __shared__ __align__(16) ushort_t Bs[128 * 128];
  int tid = threadIdx.x;
  int w = tid >> 6, lane = tid & 63;
  int row0 = blockIdx.y * 128, col0 = blockIdx.x * 128;
  int wrow = (w >> 1) * 64, wcol = (w & 1) * 64;
  int quad = lane >> 4, r16 = lane & 15;
  const ushort_t* A = a.H + a.Aofs[z];
  const ushort_t* B = a.B2[z];

  int nld = (128 * nch) >> 8;
  for (int i = 0; i < nld; i++) {
    int c = i * 256 + w * 64 + lane;
    int row = c >> rs;
    int ch = c & (nch - 1);
    int gch = ch ^ (row & mask);
    __builtin_amdgcn_global_load_lds(
        (const __attribute__((address_space(1))) uint32*)(A + (size_t)(row0 + row) * 320 + gch * 8),
        (__attribute__((address_space(3))) uint32*)&As[(i * 256 + w * 64) * 8], 16, 0, 0);
    __builtin_amdgcn_global_load_lds(
        (const __attribute__((address_space(1))) uint32*)(B + (size_t)(col0 + row) * L + gch * 8),
        (__attribute__((address_space(3))) uint32*)&Bs[(i * 256 + w * 64) * 8], 16, 0, 0);
  }
  __syncthreads();

  f32x4 acc[4][4] = {};
  int ksteps = L >> 5;
  for (int ks = 0; ks < ksteps; ks++) {
    bf16x8 af[4], bfr[4];
    #pragma unroll
    for (int i = 0; i < 4; i++) {
      int row = wrow + i * 16 + r16;
      int slot = ((ks << 2) + quad) ^ (r16 & mask);
      af[i] = *(const bf16x8*)&As[row * L + slot * 8];
    }
    #pragma unroll
    for (int j = 0; j < 4; j++) {
      int row = wcol + j * 16 + r16;
      int slot = ((ks << 2) + quad) ^ (r16 & mask);
      bfr[j] = *(const bf16x8*)&Bs[row * L + slot * 8];
    }
    #pragma unroll
    for (int i = 0; i < 4; i++)
      #pragma unroll
      for (int j = 0; j < 4; j++)
        acc[i][j] = __builtin_amdgcn_mfma_f32_16x16x32_bf16(af[i], bfr[j], acc[i][j], 0, 0, 0);
  }

  const float* bias = a.bias[z];
  float* C = a.out[z];
  #pragma unroll
  for (int i = 0; i < 4; i++) {
    #pragma unroll
    for (int j = 0; j < 4; j++) {
      int col = col0 + wcol + j * 16 + r16;
      #pragma unroll
      for (int reg = 0; reg < 4; reg++) {
        int row = row0 + wrow + i * 16 + quad * 4 + reg;
        float s = acc[i][j][reg];
        size_t idx = (size_t)row * kD + col;
        if (z == 0) {
          C[idx] = s;
        } else if (z == 1) {
          C[idx] = sigm(s + bias[col]);
        } else if (z == 2) {
          C[idx] = __expf(-0.606531f * sigm(s + bias[col]));
        } else {
          float vv = C[idx];
          C[idx] = vv + (a.vfirst[idx] - vv) * sigm(s + bias[col]);
        }
      }
    }
  }
}

// ---------------- post: kk(neg), k update, b, wr in-place, c1/c2/c3 ----------
// c12 padded to stride-4 floats per gid so the scan producer can fetch it
// with one 16B global_load_lds lane.
__global__ __launch_bounds__(256) void post_kernel(
    float* __restrict__ kArr, float* __restrict__ kkArr, float* __restrict__ bArr,
    const float* __restrict__ aArr, float* __restrict__ rArr, const float* __restrict__ wArr,
    const float* __restrict__ k_k, const float* __restrict__ k_a, const float* __restrict__ r_k,
    float* __restrict__ c12, float* __restrict__ c3)
{
  int gid = blockIdx.x * 4 + (threadIdx.x >> 6);   // t*H + h
  int lane = threadIdx.x & 63;
  int h = gid & (kH - 1);
  int d = h * kN + lane;
  size_t off = (size_t)gid * kN + lane;
  float kv = kArr[off];
  float kkv = kv * k_k[d];
  float ss = kkv * kkv;
  #pragma unroll
  for (int o = 32; o > 0; o >>= 1) ss += __shfl_xor(ss, o);
  float scale = 1.f / fmaxf(sqrtf(ss), 1e-12f);
  float kkf = kkv * scale;
  kkArr[off] = -kkf;                 // pre-negated for the scan
  float av = aArr[off];
  float bv = kkf * av;
  bArr[off] = bv;
  float knew = kv * (1.f + (av - 1.f) * k_a[d]);
  kArr[off] = knew;
  float rv = rArr[off];
  float wv = wArr[off];
  rArr[off] = wv * rv;               // in-place wr
  float p1 = bv * rv;
  float p2 = knew * rv;
  float p3 = rv * knew * r_k[d];
  #pragma unroll
  for (int o = 32; o > 0; o >>= 1) {
    p1 += __shfl_xor(p1, o); p2 += __shfl_xor(p2, o); p3 += __shfl_xor(p3, o);
  }
  if (lane == 0) {
    c12[(size_t)gid * 4]     = p1;
    c12[(size_t)gid * 4 + 1] = p2;
    c3[gid] = p3;
  }
}

// ---------------- sequential scan: 8 blocks/head, 1 producer + 2 consumers ---
// SIMD-sharing model: r3's 5 waves on 4 SIMDs put producer+consumer on one
// SIMD; the 16-step barrier locks all consumers to that laggard (286 cyc/step).
// Now 8 blocks/head x 8 rows: 192 threads = 3 waves on 4 SIMDs, no sharing,
// and 256 blocks fill all 256 CUs (was 128). Per-wave step code is identical
// to the proven r3 consumer. Producer redundancy doubles (FETCH ~100 MB, L2).
// Slot: [0,256) w/wr/k/kk | [256,320) b | [320,328) v (8 rows) | [328,330) c12.
#define SLOT_F 344   // 16B-aligned slot
#define NSLOT 32
#define PHASE 16

__device__ __forceinline__ void row_allsum2(float& x, float& y) {
  int t;
  t = __builtin_amdgcn_update_dpp(0, __float_as_int(x), 0x121, 0xF, 0xF, true);
  x += __int_as_float(t);
  t = __builtin_amdgcn_update_dpp(0, __float_as_int(y), 0x121, 0xF, 0xF, true);
  y += __int_as_float(t);
  t = __builtin_amdgcn_update_dpp(0, __float_as_int(x), 0x122, 0xF, 0xF, true);
  x += __int_as_float(t);
  t = __builtin_amdgcn_update_dpp(0, __float_as_int(y), 0x122, 0xF, 0xF, true);
  y += __int_as_float(t);
  t = __builtin_amdgcn_update_dpp(0, __float_as_int(x), 0x124, 0xF, 0xF, true);
  x += __int_as_float(t);
  t = __builtin_amdgcn_update_dpp(0, __float_as_int(y), 0x124, 0xF, 0xF, true);
  y += __int_as_float(t);
  t = __builtin_amdgcn_update_dpp(0, __float_as_int(x), 0x128, 0xF, 0xF, true);
  x += __int_as_float(t);
  t = __builtin_amdgcn_update_dpp(0, __float_as_int(y), 0x128, 0xF, 0xF, true);
  y += __int_as_float(t);
}

__global__ __launch_bounds__(192) void scan_kernel(
    const float* __restrict__ s0_in, const float* __restrict__ wA, const float* __restrict__ wrA,
    const float* __restrict__ kA, const float* __restrict__ vA, const float* __restrict__ kkA,
    const float* __restrict__ bA, const float* __restrict__ c12,
    float* __restrict__ y, float* __restrict__ s_out)
{
  __shared__ __align__(16) float ring[NSLOT * SLOT_F];
  int blk = blockIdx.x;
  // XCD grouping: the 8 blocks of head h are blk, blk+32, ..., blk+224 ->
  // all congruent mod 8 -> same XCD.
  int h = blk & 31;
  int i0 = (blk >> 5) << 3;            // 8 rows per block
  int wid = threadIdx.x >> 6;
  int lane = threadIdx.x & 63;
  int hv = h * kN;

  if (wid == 0) {
    // per-lane global sources for the two wide loads
    int sel = lane >> 4;
    const float* b1 = (sel == 0) ? wA : (sel == 1) ? wrA : (sel == 2) ? kA : kkA;
    b1 += hv + (lane & 15) * 4;
    const float* b2;
    size_t st2;
    if (lane < 16)      { b2 = bA + hv + lane * 4;             st2 = kD; }
    else if (lane < 18) { b2 = vA + hv + i0 + (lane - 16) * 4; st2 = kD; }
    else                { b2 = c12 + (size_t)h * 4;            st2 = kH * 4; }
    bool m2 = (lane < 19);

    #define ISSUE(t)                                                                       \
      {                                                                                    \
        float* sb = &ring[((t) & (NSLOT - 1)) * SLOT_F];                                   \
        __builtin_amdgcn_global_load_lds(                                                  \
            (const __attribute__((address_space(1))) uint32*)(b1 + (size_t)(t) * kD),      \
            (__attribute__((address_space(3))) uint32*)sb, 16, 0, 0);                      \
        if (m2)                                                                            \
          __builtin_amdgcn_global_load_lds(                                                \
              (const __attribute__((address_space(1))) uint32*)(b2 + (size_t)(t) * st2),   \
              (__attribute__((address_space(3))) uint32*)(sb + 256), 16, 0, 0);            \
      }
    for (int t = 0; t < PHASE; t++) ISSUE(t);
    __syncthreads();
    for (int ph = 0; ph < kS / PHASE; ph++) {
      int t0 = ph * PHASE + PHASE;
      if (t0 < kS) {
        for (int t = t0; t < t0 + PHASE; t++) ISSUE(t);
      }
      __syncthreads();
    }
    #undef ISSUE
  } else {
    int col16 = lane & 15;
    int row = lane >> 4;
    int vidx = (wid - 1) * 4 + row;    // 0..7
    int i = i0 + vidx;
    int co = col16 * 4;
    size_t srow = ((size_t)(hv + i)) * kN + co;
    float4 sS = *(const float4*)(s0_in + srow);
    float* py = y + (size_t)(hv + i);

    __syncthreads();

    float4 Aw4, Awr4, Ak4, Akk4, Ab4; float Av1, Ac1, Ac2;
    float4 Bw4, Bwr4, Bk4, Bkk4, Bb4; float Bv1, Bc1, Bc2;

    #define LOADSLOT(sl, W, WR, K, KK, B, V, C1, C2)             \
      {                                                          \
        const float* sb = &ring[(sl) * SLOT_F];                  \
        W  = *(const float4*)(sb + co);                          \
        WR = *(const float4*)(sb + 64 + co);                     \
        K  = *(const float4*)(sb + 128 + co);                    \
        KK = *(const float4*)(sb + 192 + co);                    \
        B  = *(const float4*)(sb + 256 + co);                    \
        V  = sb[320 + vidx];                                     \
        C1 = sb[328];                                            \
        C2 = sb[329];                                            \
      }
    #define STEP(W, WR, K, KK, B, V, C1, C2)                                  \
      {                                                                       \
        float sa = sS.x * KK.x + sS.y * KK.y + sS.z * KK.z + sS.w * KK.w;     \
        float u  = sS.x * WR.x + sS.y * WR.y + sS.z * WR.z + sS.w * WR.w;     \
        row_allsum2(sa, u);                                                   \
        sS.x = fmaf(sS.x, W.x, fmaf(sa, B.x, V * K.x));                       \
        sS.y = fmaf(sS.y, W.y, fmaf(sa, B.y, V * K.y));                       \
        sS.z = fmaf(sS.z, W.z, fmaf(sa, B.z, V * K.z));                       \
        sS.w = fmaf(sS.w, W.w, fmaf(sa, B.w, V * K.w));                       \
        float yv = fmaf(sa, C1, fmaf(V, C2, u));                              \
        if (col16 == 0) *py = yv;                                             \
        py += kD;                                                             \
      }

    for (int ph = 0; ph < kS / PHASE; ph++) {
      int t0 = ph * PHASE;
      LOADSLOT(t0 & (NSLOT - 1), Aw4, Awr4, Ak4, Akk4, Ab4, Av1, Ac1, Ac2);
      #pragma unroll
      for (int s = 0; s < PHASE; s += 2) {
        LOADSLOT((t0 + s + 1) & (NSLOT - 1), Bw4, Bwr4, Bk4, Bkk4, Bb4, Bv1, Bc1, Bc2);
        STEP(Aw4, Awr4, Ak4, Akk4, Ab4, Av1, Ac1, Ac2);
        if (s + 2 < PHASE)
          LOADSLOT((t0 + s + 2) & (NSLOT - 1), Aw4, Awr4, Ak4, Akk4, Ab4, Av1, Ac1, Ac2);
        STEP(Bw4, Bwr4, Bk4, Bkk4, Bb4, Bv1, Bc1, Bc2);
      }
      __syncthreads();
    }
    #undef LOADSLOT
    #undef STEP
    *(float4*)(s_out + srow) = sS;
  }
}

// ---------------- output: groupnorm(y)*lnx + c3*v, *gate → bf16 A for Wo -----
__global__ __launch_bounds__(256) void out_kernel(
    const float* __restrict__ y, const float* __restrict__ vA, const float* __restrict__ c3,
    const float* __restrict__ lnw, const float* __restrict__ lnb,
    const float* __restrict__ gate, ushort_t* __restrict__ Ay)
{
  int gid = blockIdx.x * 4 + (threadIdx.x >> 6);
  int lane = threadIdx.x & 63;
  int h = gid & (kH - 1);
  size_t off = (size_t)gid * kN + lane;
  float yv = y[off];
  float s = yv, s2 = yv * yv;
  #pragma unroll
  for (int o = 32; o > 0; o >>= 1) { s += __shfl_xor(s, o); s2 += __shfl_xor(s2, o); }
  float mean = s * (1.f / kN);
  float var = s2 * (1.f / kN) - mean * mean;
  float o1 = (yv - mean) * rsqrtf(var + 0.00064f);
  int d = h * kN + lane;
  float ov = o1 * lnw[d] + lnb[d];
  float rkv = c3[gid] * vA[off];
  Ay[off] = f2bf((ov + rkv) * gate[off]);
}

extern "C" void kernel_launch(void* const* d_in, const int* in_sizes, int n_in,
                              void* d_out, int out_size, void* d_ws, size_t ws_size,
                              hipStream_t stream)
{
  const float* x      = (const float*)d_in[0];
  const float* state1 = (const float*)d_in[1];
  const float* state2 = (const float*)d_in[2];
  const float* vfirst = (const float*)d_in[3];
  const float* ln1w   = (const float*)d_in[4];
  const float* ln1b   = (const float*)d_in[5];
  const float* xr_c   = (const float*)d_in[6];
  const float* xw_c   = (const float*)d_in[7];
  const float* xk_c   = (const float*)d_in[8];
  const float* xv_c   = (const float*)d_in[9];
  const float* xa_c   = (const float*)d_in[10];
  const float* xg_c   = (const float*)d_in[11];
  const float* Wr     = (const float*)d_in[12];
  const float* Wk     = (const float*)d_in[13];
  const float* Wv     = (const float*)d_in[14];
  const float* Wo     = (const float*)d_in[15];
  const float* w1     = (const float*)d_in[16];
  const float* w2     = (const float*)d_in[17];
  const float* w0     = (const float*)d_in[18];
  const float* a1     = (const float*)d_in[19];
  const float* a2     = (const float*)d_in[20];
  const float* a0     = (const float*)d_in[21];
  const float* g1     = (const float*)d_in[22];
  const float* g2     = (const float*)d_in[23];
  const float* v1     = (const float*)d_in[24];
  const float* v2     = (const float*)d_in[25];
  const float* v0     = (const float*)d_in[26];
  const float* k_k    = (const float*)d_in[27];
  const float* k_a    = (const float*)d_in[28];
  const float* r_k    = (const float*)d_in[29];
  const float* lnxw   = (const float*)d_in[30];
  const float* lnxb   = (const float*)d_in[31];

  float* out0  = (float*)d_out;
  float* s1out = out0 + (size_t)kS * kD;
  float* s2out = s1out + kD;

  size_t SD = (size_t)kS * kD;
  float* ws  = (float*)d_ws;
  float* xnB = ws;                 // bf16 xn + bf16 xprev; c12/c3 after gemm1
  float* rB  = ws + SD;
  float* kB  = ws + 2 * SD;
  float* vB  = ws + 3 * SD;
  float* wB  = ws + 4 * SD;
  float* aB  = ws + 5 * SD;
  float* kkB = ws + 6 * SD;
  float* bB  = ws + 7 * SD;
  float* gB  = ws + 8 * SD;
  float* yB  = ws + 9 * SD;

  ushort_t* xnbf    = (ushort_t*)xnB;
  ushort_t* xprevbf = (ushort_t*)xnB + SD;
  ushort_t* ArB = (ushort_t*)kkB;        // dead before post writes kkB
  ushort_t* AkB = (ushort_t*)kkB + SD;
  ushort_t* AvB = (ushort_t*)bB;         // bB first half
  ushort_t* B1  = (ushort_t*)bB + SD;    // bB second half: B1 | H | B2
  ushort_t* Hbuf = B1 + (size_t)320 * 4096;
  ushort_t* B2g  = Hbuf + (size_t)2048 * 320;
  ushort_t* B2a  = B2g + (size_t)2048 * 128;
  ushort_t* B2w  = B2a + (size_t)2048 * 64;
  ushort_t* B2v  = B2w + (size_t)2048 * 64;
  ushort_t* WrB = (ushort_t*)yB;         // dead before scan writes yB
  ushort_t* WkB = (ushort_t*)yB + SD;
  ushort_t* WvB = (ushort_t*)gB;         // dead before gemm2 writes gB
  ushort_t* AyB = (ushort_t*)aB;         // aB dead after post
  ushort_t* WoB = (ushort_t*)rB;         // rB (wr) dead after scan
  // c12/c3 live in the xn region (dead after gemm1, before post)
  float* c12B = xnB;                                   // stride-4 per gid
  float* c3B  = xnB + (size_t)kS * kH * 4;

  ln1_kernel<<<kS, 256, 0, stream>>>(x, ln1w, ln1b, xnbf, xprevbf, state1, s1out);
  mix3_cvt<<<kS, 256, 0, stream>>>(xnbf, xprevbf, xr_c, xk_c, xv_c, ArB, AkB, AvB);

  const int CVT_BLKS = (int)(SD / 4 / 256);
  {
    CvtArgs ca;
    ca.src[0] = Wr; ca.src[1] = Wk; ca.src[2] = Wv;
    ca.dst[0] = WrB; ca.dst[1] = WkB; ca.dst[2] = WvB;
    cvt_bf16_b<<<dim3(CVT_BLKS, 3), 256, 0, stream>>>(ca);
  }
  {
    PrepW1Args pa;
    pa.w1[0] = g1; pa.w1[1] = a1; pa.w1[2] = w1; pa.w1[3] = v1;
    pa.c[0] = xg_c; pa.c[1] = xa_c; pa.c[2] = xw_c; pa.c[3] = xv_c;
    pa.B1 = B1;
    prep_w1<<<dim3(64, 20), 256, 0, stream>>>(pa);
  }
  {
    PrepW2Args pa;
    pa.w2[0] = g2; pa.w2[1] = a2; pa.w2[2] = w2; pa.w2[3] = v2;
    pa.B2[0] = B2g; pa.B2[1] = B2a; pa.B2[2] = B2w; pa.B2[3] = B2v;
    pa.L[0] = 128; pa.L[1] = 64; pa.L[2] = 64; pa.L[3] = 32;
    prep_w2<<<dim3(32, 8, 4), 256, 0, stream>>>(pa);
  }
  {
    GemmArgs ga;
    ga.A[0] = ArB; ga.A[1] = AkB; ga.A[2] = AvB;
    ga.B[0] = WrB; ga.B[1] = WkB; ga.B[2] = WvB;
    ga.C[0] = rB;  ga.C[1] = kB;  ga.C[2] = vB;
    ga.resid[0] = nullptr; ga.resid[1] = nullptr; ga.resid[2] = nullptr;
    gemm_bf16_b<<<dim3(16, 16, 3), 256, 0, stream>>>(ga);
  }

  gemm1_kernel<<<dim3(5, 16), 256, 0, stream>>>(xnbf, xprevbf, B1, Hbuf);
  {
    Gemm2Args ga;
    ga.H = Hbuf;
    ga.B2[0] = B2g; ga.B2[1] = B2a; ga.B2[2] = B2w; ga.B2[3] = B2v;
    ga.Aofs[0] = 0; ga.Aofs[1] = 128; ga.Aofs[2] = 192; ga.Aofs[3] = 256;
    ga.L[0] = 128; ga.L[1] = 64; ga.L[2] = 64; ga.L[3] = 32;
    ga.bias[0] = nullptr; ga.bias[1] = a0; ga.bias[2] = w0; ga.bias[3] = v0;
    ga.out[0] = gB; ga.out[1] = aB; ga.out[2] = wB; ga.out[3] = vB;
    ga.vfirst = vfirst;
    gemm2_kernel<<<dim3(16, 16, 4), 256, 0, stream>>>(ga);
  }

  post_kernel<<<kS * kH / 4, 256, 0, stream>>>(kB, kkB, bB, aB, rB, wB,
                                               k_k, k_a, r_k, c12B, c3B);

  scan_kernel<<<kH * 8, 192, 0, stream>>>(state2, wB, rB, kB, vB, kkB, bB, c12B, yB, s2out);

  out_kernel<<<kS * kH / 4, 256, 0, stream>>>(yB, vB, c3B, lnxw, lnxb, gB, AyB);

  {
    CvtArgs ca;
    ca.src[0] = Wo; ca.src[1] = Wo; ca.src[2] = Wo;
    ca.dst[0] = WoB; ca.dst[1] = WoB; ca.dst[2] = WoB;
    cvt_bf16_b<<<dim3(CVT_BLKS, 1), 256, 0, stream>>>(ca);
  }
  {
    GemmArgs ga;
    ga.A[0] = AyB; ga.A[1] = AyB; ga.A[2] = AyB;
    ga.B[0] = WoB; ga.B[1] = WoB; ga.B[2] = WoB;
    ga.C[0] = out0; ga.C[1] = out0; ga.C[2] = out0;
    ga.resid[0] = x; ga.resid[1] = x; ga.resid[2] = x;
    gemm_bf16_b<<<dim3(16, 16, 1), 256, 0, stream>>>(ga);
  }
}

// Round 10
// 724.837 us; speedup vs baseline: 1.0098x; 1.0098x over previous
//
#include <hip/hip_runtime.h>
#include <math.h>

#define kD 2048
#define kH 32
#define kN 64
#define kS 2048

typedef unsigned short ushort_t;
typedef unsigned int uint32;

__device__ __forceinline__ ushort_t f2bf(float f) {
  uint32 u = __float_as_uint(f);
  u += 0x7fffu + ((u >> 16) & 1u);   // RNE
  return (ushort_t)(u >> 16);
}
__device__ __forceinline__ float bf2f(ushort_t u) {
  return __uint_as_float(((uint32)u) << 16);
}
__device__ __forceinline__ float sigm(float x) { return 1.f / (1.f + __expf(-x)); }

// ---------------- LayerNorm (ln1): vectorized (8 elem/thread) ----------------
__global__ __launch_bounds__(256) void ln1_kernel(
    const float* __restrict__ x, const float* __restrict__ w, const float* __restrict__ b,
    ushort_t* __restrict__ xnbf, ushort_t* __restrict__ xprevbf,
    const float* __restrict__ state1, float* __restrict__ state1_out)
{
  int t = blockIdx.x;
  const float* row = x + (size_t)t * kD;
  int d0 = threadIdx.x * 8;
  float4 v0 = *(const float4*)(row + d0);
  float4 v1 = *(const float4*)(row + d0 + 4);
  float vv[8] = { v0.x, v0.y, v0.z, v0.w, v1.x, v1.y, v1.z, v1.w };
  float s = 0.f, s2 = 0.f;
  #pragma unroll
  for (int j = 0; j < 8; j++) { s += vv[j]; s2 += vv[j] * vv[j]; }
  #pragma unroll
  for (int o = 32; o > 0; o >>= 1) { s += __shfl_down(s, o); s2 += __shfl_down(s2, o); }
  __shared__ float ls[4], ls2[4];
  int wid = threadIdx.x >> 6;
  if ((threadIdx.x & 63) == 0) { ls[wid] = s; ls2[wid] = s2; }
  __syncthreads();
  s = ls[0] + ls[1] + ls[2] + ls[3];
  s2 = ls2[0] + ls2[1] + ls2[2] + ls2[3];
  float mean = s * (1.f / kD);
  float var = s2 * (1.f / kD) - mean * mean;
  float rstd = rsqrtf(var + 1e-5f);
  float4 w0 = *(const float4*)(w + d0), w1 = *(const float4*)(w + d0 + 4);
  float4 b0 = *(const float4*)(b + d0), b1 = *(const float4*)(b + d0 + 4);
  float ww[8] = { w0.x, w0.y, w0.z, w0.w, w1.x, w1.y, w1.z, w1.w };
  float bb[8] = { b0.x, b0.y, b0.z, b0.w, b1.x, b1.y, b1.z, b1.w };
  float o8[8];
  ushort_t ob[8];
  #pragma unroll
  for (int j = 0; j < 8; j++) {
    o8[j] = (vv[j] - mean) * rstd * ww[j] + bb[j];
    ob[j] = f2bf(o8[j]);
  }
  *(uint4*)(xnbf + (size_t)t * kD + d0) = *(const uint4*)ob;
  if (t < kS - 1) {
    *(uint4*)(xprevbf + (size_t)(t + 1) * kD + d0) = *(const uint4*)ob;
  } else {
    *(float4*)(state1_out + d0)     = make_float4(o8[0], o8[1], o8[2], o8[3]);
    *(float4*)(state1_out + d0 + 4) = make_float4(o8[4], o8[5], o8[6], o8[7]);
  }
  if (t == 0) {
    float4 s0 = *(const float4*)(state1 + d0);
    float4 s1 = *(const float4*)(state1 + d0 + 4);
    float sv[8] = { s0.x, s0.y, s0.z, s0.w, s1.x, s1.y, s1.z, s1.w };
    ushort_t sb[8];
    #pragma unroll
    for (int j = 0; j < 8; j++) sb[j] = f2bf(sv[j]);
    *(uint4*)(xprevbf + d0) = *(const uint4*)sb;
  }
}

// ---------------- mix + bf16 convert, vectorized (8 elem/thread) -------------
__global__ __launch_bounds__(256) void mix3_cvt(
    const ushort_t* __restrict__ xnbf, const ushort_t* __restrict__ xprevbf,
    const float* __restrict__ cr, const float* __restrict__ ck, const float* __restrict__ cv,
    ushort_t* __restrict__ Ar, ushort_t* __restrict__ Ak, ushort_t* __restrict__ Av)
{
  int t = blockIdx.x;
  size_t base = (size_t)t * kD;
  int d0 = threadIdx.x * 8;
  uint4 xa = *(const uint4*)(xnbf + base + d0);
  uint4 xb = *(const uint4*)(xprevbf + base + d0);
  const ushort_t* pa = (const ushort_t*)&xa;
  const ushort_t* pb = (const ushort_t*)&xb;
  float c8[8], dx[8];
  #pragma unroll
  for (int j = 0; j < 8; j++) {
    c8[j] = bf2f(pa[j]);
    dx[j] = bf2f(pb[j]) - c8[j];
  }
  float4 r0 = *(const float4*)(cr + d0), r1 = *(const float4*)(cr + d0 + 4);
  float4 k0 = *(const float4*)(ck + d0), k1 = *(const float4*)(ck + d0 + 4);
  float4 v0 = *(const float4*)(cv + d0), v1 = *(const float4*)(cv + d0 + 4);
  float rr[8] = { r0.x, r0.y, r0.z, r0.w, r1.x, r1.y, r1.z, r1.w };
  float kk[8] = { k0.x, k0.y, k0.z, k0.w, k1.x, k1.y, k1.z, k1.w };
  float vv[8] = { v0.x, v0.y, v0.z, v0.w, v1.x, v1.y, v1.z, v1.w };
  ushort_t orr[8], okk[8], ovv[8];
  #pragma unroll
  for (int j = 0; j < 8; j++) {
    orr[j] = f2bf(c8[j] + dx[j] * rr[j]);
    okk[j] = f2bf(c8[j] + dx[j] * kk[j]);
    ovv[j] = f2bf(c8[j] + dx[j] * vv[j]);
  }
  *(uint4*)(Ar + base + d0) = *(const uint4*)orr;
  *(uint4*)(Ak + base + d0) = *(const uint4*)okk;
  *(uint4*)(Av + base + d0) = *(const uint4*)ovv;
}

// ---------------- batched fp32 -> bf16 ----------------
struct CvtArgs { const float* src[3]; ushort_t* dst[3]; };
__global__ __launch_bounds__(256) void cvt_bf16_b(CvtArgs args)
{
  const float* in = args.src[blockIdx.y];
  ushort_t* out = args.dst[blockIdx.y];
  int idx = blockIdx.x * 256 + threadIdx.x;
  float4 v = ((const float4*)in)[idx];
  ushort_t o[4] = { f2bf(v.x), f2bf(v.y), f2bf(v.z), f2bf(v.w) };
  ((uint2*)out)[idx] = *(const uint2*)o;
}

// ---------------- batched bf16 MFMA NT GEMM (128x128, BK=64) ----------------
typedef __bf16 bf16x8 __attribute__((ext_vector_type(8)));
typedef float f32x4 __attribute__((ext_vector_type(4)));

struct GemmArgs {
  const ushort_t* A[3];
  const ushort_t* B[3];
  float* C[3];
  const float* resid[3];
};

__global__ __launch_bounds__(256) void gemm_bf16_b(GemmArgs args)
{
  int z = blockIdx.z;
  const ushort_t* __restrict__ A = args.A[z];
  const ushort_t* __restrict__ B = args.B[z];
  float* __restrict__ C = args.C[z];
  const float* __restrict__ resid = args.resid[z];

  __shared__ __align__(16) ushort_t As[128 * 64];
  __shared__ __align__(16) ushort_t Bs[128 * 64];
  int tid = threadIdx.x;
  int w = tid >> 6, lane = tid & 63;
  int row0 = blockIdx.y * 128, col0 = blockIdx.x * 128;
  int wrow = (w >> 1) * 64, wcol = (w & 1) * 64;
  int quad = lane >> 4, r16 = lane & 15;
  f32x4 acc[4][4] = {};

  int lrow = lane >> 3;
  int lsw  = (lane & 7) ^ lrow;

  for (int k0 = 0; k0 < kD; k0 += 64) {
    #pragma unroll
    for (int n = 0; n < 4; n++) {
      int rr = w * 32 + n * 8 + lrow;
      int cc = k0 + lsw * 8;
      const ushort_t* ga = A + (size_t)(row0 + rr) * kD + cc;
      const ushort_t* gb = B + (size_t)(col0 + rr) * kD + cc;
      __builtin_amdgcn_global_load_lds(
          (const __attribute__((address_space(1))) uint32*)ga,
          (__attribute__((address_space(3))) uint32*)&As[(w * 32 + n * 8) * 64], 16, 0, 0);
      __builtin_amdgcn_global_load_lds(
          (const __attribute__((address_space(1))) uint32*)gb,
          (__attribute__((address_space(3))) uint32*)&Bs[(w * 32 + n * 8) * 64], 16, 0, 0);
    }
    __syncthreads();
    #pragma unroll
    for (int kk = 0; kk < 64; kk += 32) {
      bf16x8 af[4], bfr[4];
      #pragma unroll
      for (int i = 0; i < 4; i++) {
        int row = wrow + i * 16 + r16;
        int chunk = ((kk >> 3) + quad) ^ (r16 & 7);
        af[i] = *(const bf16x8*)&As[row * 64 + chunk * 8];
      }
      #pragma unroll
      for (int j = 0; j < 4; j++) {
        int row = wcol + j * 16 + r16;
        int chunk = ((kk >> 3) + quad) ^ (r16 & 7);
        bfr[j] = *(const bf16x8*)&Bs[row * 64 + chunk * 8];
      }
      #pragma unroll
      for (int i = 0; i < 4; i++)
        #pragma unroll
        for (int j = 0; j < 4; j++)
          acc[i][j] = __builtin_amdgcn_mfma_f32_16x16x32_bf16(af[i], bfr[j], acc[i][j], 0, 0, 0);
    }
    __syncthreads();
  }
  #pragma unroll
  for (int i = 0; i < 4; i++) {
    #pragma unroll
    for (int j = 0; j < 4; j++) {
      int col = col0 + wcol + j * 16 + r16;
      #pragma unroll
      for (int reg = 0; reg < 4; reg++) {
        int row = row0 + wrow + i * 16 + quad * 4 + reg;
        float v = acc[i][j][reg];
        if (resid) v += resid[(size_t)row * kD + col];
        C[(size_t)row * kD + col] = v;
      }
    }
  }
}

// ---------------- prep W1cat: B1[col][k] (320 x 4096 bf16) -------------------
struct PrepW1Args { const float* w1[4]; const float* c[4]; ushort_t* B1; };
__global__ __launch_bounds__(256) void prep_w1(PrepW1Args a)
{
  __shared__ float tile[64][17];
  int k0 = blockIdx.x * 64;
  int col0 = blockIdx.y * 16;
  int z, lc0, L;
  if (col0 < 128)      { z = 0; lc0 = col0;       L = 128; }
  else if (col0 < 192) { z = 1; lc0 = col0 - 128; L = 64; }
  else if (col0 < 256) { z = 2; lc0 = col0 - 192; L = 64; }
  else if (col0 < 288) { z = 3; lc0 = col0 - 256; L = 32; }
  else z = -1;
  int tid = threadIdx.x;
  if (z >= 0) {
    const float* W = a.w1[z];
    const float* C = a.c[z];
    int cc = tid & 15, kk = tid >> 4;
    #pragma unroll
    for (int i = 0; i < 4; i++) {
      int k = k0 + kk + i * 16;
      int ksrc = k & (kD - 1);
      float cv = C[ksrc];
      float sc = (k < kD) ? (1.f - cv) : cv;
      tile[kk + i * 16][cc] = W[(size_t)ksrc * L + lc0 + cc] * sc;
    }
  }
  __syncthreads();
  int kk2 = tid & 63, cc2 = tid >> 6;
  #pragma unroll
  for (int i = 0; i < 4; i++) {
    int col = col0 + cc2 * 4 + i;
    float v = (z >= 0) ? tile[kk2][cc2 * 4 + i] : 0.f;
    a.B1[(size_t)col * 4096 + k0 + kk2] = f2bf(v);
  }
}

// ---------------- prep W2: per-z transpose (L x 2048 -> 2048 x L bf16) -------
struct PrepW2Args { const float* w2[4]; ushort_t* B2[4]; int L[4]; };
__global__ __launch_bounds__(256) void prep_w2(PrepW2Args a)
{
  __shared__ float tile[64][17];
  int z = blockIdx.z;
  int L = a.L[z];
  int l0 = blockIdx.y * 16;
  if (l0 >= L) return;
  int j0 = blockIdx.x * 64;
  int tid = threadIdx.x;
  const float* W = a.w2[z];
  ushort_t* out = a.B2[z];
  int jj = tid & 63;
  #pragma unroll
  for (int i = 0; i < 4; i++) {
    int ll = (tid >> 6) * 4 + i;
    tile[jj][ll] = W[(size_t)(l0 + ll) * kD + j0 + jj];
  }
  __syncthreads();
  int ll2 = tid & 15;
  #pragma unroll
  for (int i = 0; i < 4; i++) {
    int jj2 = (tid >> 4) + i * 16;
    out[(size_t)(j0 + jj2) * L + l0 + ll2] = f2bf(tile[jj2][ll2]);
  }
}

// ---------------- GEMM1: H = [xn | xprev] @ B1cat^T  (2048 x 4096 x 320) -----
__global__ __launch_bounds__(256) void gemm1_kernel(
    const ushort_t* __restrict__ xnbf, const ushort_t* __restrict__ xprevbf,
    const ushort_t* __restrict__ B1, ushort_t* __restrict__ H)
{
  __shared__ __align__(16) ushort_t As[128 * 64];
  __shared__ __align__(16) ushort_t Bs[64 * 64];
  int tid = threadIdx.x;
  int w = tid >> 6, lane = tid & 63;
  int col0 = blockIdx.x * 64, row0 = blockIdx.y * 128;
  int quad = lane >> 4, r16 = lane & 15;
  f32x4 acc[2][4] = {};
  int lrow = lane >> 3;
  int lsw = (lane & 7) ^ lrow;

  for (int k0 = 0; k0 < 4096; k0 += 64) {
    const ushort_t* Abase = (k0 < kD) ? (xnbf + k0) : (xprevbf + (k0 - kD));
    #pragma unroll
    for (int n = 0; n < 4; n++) {
      int rr = w * 32 + n * 8 + lrow;
      const ushort_t* ga = Abase + (size_t)(row0 + rr) * kD + lsw * 8;
      __builtin_amdgcn_global_load_lds(
          (const __attribute__((address_space(1))) uint32*)ga,
          (__attribute__((address_space(3))) uint32*)&As[(w * 32 + n * 8) * 64], 16, 0, 0);
    }
    #pragma unroll
    for (int n = 0; n < 2; n++) {
      int rr = w * 16 + n * 8 + lrow;
      const ushort_t* gb = B1 + (size_t)(col0 + rr) * 4096 + k0 + lsw * 8;
      __builtin_amdgcn_global_load_lds(
          (const __attribute__((address_space(1))) uint32*)gb,
          (__attribute__((address_space(3))) uint32*)&Bs[(w * 16 + n * 8) * 64], 16, 0, 0);
    }
    __syncthreads();
    #pragma unroll
    for (int kk = 0; kk < 64; kk += 32) {
      bf16x8 af[2], bfr[4];
      #pragma unroll
      for (int i = 0; i < 2; i++) {
        int row = w * 32 + i * 16 + r16;
        int chunk = ((kk >> 3) + quad) ^ (r16 & 7);
        af[i] = *(const bf16x8*)&As[row * 64 + chunk * 8];
      }
      #pragma unroll
      for (int j = 0; j < 4; j++) {
        int row = j * 16 + r16;
        int chunk = ((kk >> 3) + quad) ^ (r16 & 7);
        bfr[j] = *(const bf16x8*)&Bs[row * 64 + chunk * 8];
      }
      #pragma unroll
      for (int i = 0; i < 2; i++)
        #pragma unroll
        for (int j = 0; j < 4; j++)
          acc[i][j] = __builtin_amdgcn_mfma_f32_16x16x32_bf16(af[i], bfr[j], acc[i][j], 0, 0, 0);
    }
    __syncthreads();
  }
  #pragma unroll
  for (int i = 0; i < 2; i++) {
    #pragma unroll
    for (int j = 0; j < 4; j++) {
      int col = col0 + j * 16 + r16;
      #pragma unroll
      for (int reg = 0; reg < 4; reg++) {
        int row = row0 + w * 32 + i * 16 + quad * 4 + reg;
        float v = acc[i][j][reg];
        if (col < 128) v = sigm(v);
        else if (col >= 192 && col < 256) v = tanhf(v);
        H[(size_t)row * 320 + col] = f2bf(v);
      }
    }
  }
}

// ---------------- GEMM2 (z-batched, K=Lz): out = act(H_z @ W2_z + bias) ------
struct Gemm2Args {
  const ushort_t* H;
  const ushort_t* B2[4];
  int Aofs[4];
  int L[4];
  const float* bias[4];
  float* out[4];
  const float* vfirst;
};
__global__ __launch_bounds__(256) void gemm2_kernel(Gemm2Args a)
{
  int z = blockIdx.z;
  int L = a.L[z];
  int nch = L >> 3;
  int rs = __builtin_ctz(nch);
  int mask = (nch >= 8) ? 7 : (nch - 1);
  __shared__ __align__(16) ushort_t As[128 * 128];
  __shared__ __align__(16) ushort_t Bs[128 * 128];
  int tid = threadIdx.x;
  int w = tid >> 6, lane = tid & 63;
  int row0 = blockIdx.y * 128, col0 = blockIdx.x * 128;
  int wrow = (w >> 1) * 64, wcol = (w & 1) * 64;
  int quad = lane >> 4, r16 = lane & 15;
  const ushort_t* A = a.H + a.Aofs[z];
  const ushort_t* B = a.B2[z];

  int nld = (128 * nch) >> 8;
  for (int i = 0; i < nld; i++) {
    int c = i * 256 + w * 64 + lane;
    int row = c >> rs;
    int ch = c & (nch - 1);
    int gch = ch ^ (row & mask);
    __builtin_amdgcn_global_load_lds(
        (const __attribute__((address_space(1))) uint32*)(A + (size_t)(row0 + row) * 320 + gch * 8),
        (__attribute__((address_space(3))) uint32*)&As[(i * 256 + w * 64) * 8], 16, 0, 0);
    __builtin_amdgcn_global_load_lds(
        (const __attribute__((address_space(1))) uint32*)(B + (size_t)(col0 + row) * L + gch * 8),
        (__attribute__((address_space(3))) uint32*)&Bs[(i * 256 + w * 64) * 8], 16, 0, 0);
  }
  __syncthreads();

  f32x4 acc[4][4] = {};
  int ksteps = L >> 5;
  for (int ks = 0; ks < ksteps; ks++) {
    bf16x8 af[4], bfr[4];
    #pragma unroll
    for (int i = 0; i < 4; i++) {
      int row = wrow + i * 16 + r16;
      int slot = ((ks << 2) + quad) ^ (r16 & mask);
      af[i] = *(const bf16x8*)&As[row * L + slot * 8];
    }
    #pragma unroll
    for (int j = 0; j < 4; j++) {
      int row = wcol + j * 16 + r16;
      int slot = ((ks << 2) + quad) ^ (r16 & mask);
      bfr[j] = *(const bf16x8*)&Bs[row * L + slot * 8];
    }
    #pragma unroll
    for (int i = 0; i < 4; i++)
      #pragma unroll
      for (int j = 0; j < 4; j++)
        acc[i][j] = __builtin_amdgcn_mfma_f32_16x16x32_bf16(af[i], bfr[j], acc[i][j], 0, 0, 0);
  }

  const float* bias = a.bias[z];
  float* C = a.out[z];
  #pragma unroll
  for (int i = 0; i < 4; i++) {
    #pragma unroll
    for (int j = 0; j < 4; j++) {
      int col = col0 + wcol + j * 16 + r16;
      #pragma unroll
      for (int reg = 0; reg < 4; reg++) {
        int row = row0 + wrow + i * 16 + quad * 4 + reg;
        float s = acc[i][j][reg];
        size_t idx = (size_t)row * kD + col;
        if (z == 0) {
          C[idx] = s;
        } else if (z == 1) {
          C[idx] = sigm(s + bias[col]);
        } else if (z == 2) {
          C[idx] = __expf(-0.606531f * sigm(s + bias[col]));
        } else {
          float vv = C[idx];
          C[idx] = vv + (a.vfirst[idx] - vv) * sigm(s + bias[col]);
        }
      }
    }
  }
}

// ---------------- post: kk(neg), k update, b, wr in-place, c1/c2/c3 ----------
// c12 padded to stride-4 floats per gid so the scan producer can fetch it
// with one 16B global_load_lds lane.
__global__ __launch_bounds__(256) void post_kernel(
    float* __restrict__ kArr, float* __restrict__ kkArr, float* __restrict__ bArr,
    const float* __restrict__ aArr, float* __restrict__ rArr, const float* __restrict__ wArr,
    const float* __restrict__ k_k, const float* __restrict__ k_a, const float* __restrict__ r_k,
    float* __restrict__ c12, float* __restrict__ c3)
{
  int gid = blockIdx.x * 4 + (threadIdx.x >> 6);   // t*H + h
  int lane = threadIdx.x & 63;
  int h = gid & (kH - 1);
  int d = h * kN + lane;
  size_t off = (size_t)gid * kN + lane;
  float kv = kArr[off];
  float kkv = kv * k_k[d];
  float ss = kkv * kkv;
  #pragma unroll
  for (int o = 32; o > 0; o >>= 1) ss += __shfl_xor(ss, o);
  float scale = 1.f / fmaxf(sqrtf(ss), 1e-12f);
  float kkf = kkv * scale;
  kkArr[off] = -kkf;                 // pre-negated for the scan
  float av = aArr[off];
  float bv = kkf * av;
  bArr[off] = bv;
  float knew = kv * (1.f + (av - 1.f) * k_a[d]);
  kArr[off] = knew;
  float rv = rArr[off];
  float wv = wArr[off];
  rArr[off] = wv * rv;               // in-place wr
  float p1 = bv * rv;
  float p2 = knew * rv;
  float p3 = rv * knew * r_k[d];
  #pragma unroll
  for (int o = 32; o > 0; o >>= 1) {
    p1 += __shfl_xor(p1, o); p2 += __shfl_xor(p2, o); p3 += __shfl_xor(p3, o);
  }
  if (lane == 0) {
    c12[(size_t)gid * 4]     = p1;
    c12[(size_t)gid * 4 + 1] = p2;
    c3[gid] = p3;
  }
}

// ---------------- sequential scan: 8 blocks/head, depth-4 consumer prefetch --
// Step cost is invariant at ~286 cyc across producer/occupancy configs ->
// the residual is in-wave: issue + dep chain + per-step exposed lgkm latency
// (A/B 2-deep prefetch gives only ~1-step distance vs ~120cy ds_read latency).
// Fix: 4 rotating consumer buffers, prefetch distance 4 WITHIN the 16-slot
// window (steps 12-15 use buffers loaded at steps 8-11; no window crossing,
// producer protocol unchanged from the proven r9 structure).
#define SLOT_F 344   // 16B-aligned slot
#define NSLOT 32
#define PHASE 16

__device__ __forceinline__ void row_allsum2(float& x, float& y) {
  int t;
  t = __builtin_amdgcn_update_dpp(0, __float_as_int(x), 0x121, 0xF, 0xF, true);
  x += __int_as_float(t);
  t = __builtin_amdgcn_update_dpp(0, __float_as_int(y), 0x121, 0xF, 0xF, true);
  y += __int_as_float(t);
  t = __builtin_amdgcn_update_dpp(0, __float_as_int(x), 0x122, 0xF, 0xF, true);
  x += __int_as_float(t);
  t = __builtin_amdgcn_update_dpp(0, __float_as_int(y), 0x122, 0xF, 0xF, true);
  y += __int_as_float(t);
  t = __builtin_amdgcn_update_dpp(0, __float_as_int(x), 0x124, 0xF, 0xF, true);
  x += __int_as_float(t);
  t = __builtin_amdgcn_update_dpp(0, __float_as_int(y), 0x124, 0xF, 0xF, true);
  y += __int_as_float(t);
  t = __builtin_amdgcn_update_dpp(0, __float_as_int(x), 0x128, 0xF, 0xF, true);
  x += __int_as_float(t);
  t = __builtin_amdgcn_update_dpp(0, __float_as_int(y), 0x128, 0xF, 0xF, true);
  y += __int_as_float(t);
}

struct SBuf { float4 W, WR, K, KK, Bb; float V, C1, C2; };

__global__ __launch_bounds__(192) void scan_kernel(
    const float* __restrict__ s0_in, const float* __restrict__ wA, const float* __restrict__ wrA,
    const float* __restrict__ kA, const float* __restrict__ vA, const float* __restrict__ kkA,
    const float* __restrict__ bA, const float* __restrict__ c12,
    float* __restrict__ y, float* __restrict__ s_out)
{
  __shared__ __align__(16) float ring[NSLOT * SLOT_F];
  int blk = blockIdx.x;
  // XCD grouping: the 8 blocks of head h are blk, blk+32, ..., blk+224 ->
  // all congruent mod 8 -> same XCD.
  int h = blk & 31;
  int i0 = (blk >> 5) << 3;            // 8 rows per block
  int wid = threadIdx.x >> 6;
  int lane = threadIdx.x & 63;
  int hv = h * kN;

  if (wid == 0) {
    // per-lane global sources for the two wide loads
    int sel = lane >> 4;
    const float* b1 = (sel == 0) ? wA : (sel == 1) ? wrA : (sel == 2) ? kA : kkA;
    b1 += hv + (lane & 15) * 4;
    const float* b2;
    size_t st2;
    if (lane < 16)      { b2 = bA + hv + lane * 4;             st2 = kD; }
    else if (lane < 18) { b2 = vA + hv + i0 + (lane - 16) * 4; st2 = kD; }
    else                { b2 = c12 + (size_t)h * 4;            st2 = kH * 4; }
    bool m2 = (lane < 19);

    #define ISSUE(t)                                                                       \
      {                                                                                    \
        float* sb = &ring[((t) & (NSLOT - 1)) * SLOT_F];                                   \
        __builtin_amdgcn_global_load_lds(                                                  \
            (const __attribute__((address_space(1))) uint32*)(b1 + (size_t)(t) * kD),      \
            (__attribute__((address_space(3))) uint32*)sb, 16, 0, 0);                      \
        if (m2)                                                                            \
          __builtin_amdgcn_global_load_lds(                                                \
              (const __attribute__((address_space(1))) uint32*)(b2 + (size_t)(t) * st2),   \
              (__attribute__((address_space(3))) uint32*)(sb + 256), 16, 0, 0);            \
      }
    for (int t = 0; t < PHASE; t++) ISSUE(t);
    __syncthreads();
    for (int ph = 0; ph < kS / PHASE; ph++) {
      int t0 = ph * PHASE + PHASE;
      if (t0 < kS) {
        for (int t = t0; t < t0 + PHASE; t++) ISSUE(t);
      }
      __syncthreads();
    }
    #undef ISSUE
  } else {
    int col16 = lane & 15;
    int row = lane >> 4;
    int vidx = (wid - 1) * 4 + row;    // 0..7
    int i = i0 + vidx;
    int co = col16 * 4;
    size_t srow = ((size_t)(hv + i)) * kN + co;
    float4 sS = *(const float4*)(s0_in + srow);
    float* py = y + (size_t)(hv + i);

    __syncthreads();

    SBuf q0, q1, q2, q3;

    #define LOADSLOT(sl, S)                                      \
      {                                                          \
        const float* sb = &ring[(sl) * SLOT_F];                  \
        S.W  = *(const float4*)(sb + co);                        \
        S.WR = *(const float4*)(sb + 64 + co);                   \
        S.K  = *(const float4*)(sb + 128 + co);                  \
        S.KK = *(const float4*)(sb + 192 + co);                  \
        S.Bb = *(const float4*)(sb + 256 + co);                  \
        S.V  = sb[320 + vidx];                                   \
        S.C1 = sb[328];                                          \
        S.C2 = sb[329];                                          \
      }
    #define STEP(S)                                                           \
      {                                                                       \
        float sa = sS.x * S.KK.x + sS.y * S.KK.y + sS.z * S.KK.z + sS.w * S.KK.w; \
        float u  = sS.x * S.WR.x + sS.y * S.WR.y + sS.z * S.WR.z + sS.w * S.WR.w; \
        row_allsum2(sa, u);                                                   \
        sS.x = fmaf(sS.x, S.W.x, fmaf(sa, S.Bb.x, S.V * S.K.x));              \
        sS.y = fmaf(sS.y, S.W.y, fmaf(sa, S.Bb.y, S.V * S.K.y));              \
        sS.z = fmaf(sS.z, S.W.z, fmaf(sa, S.Bb.z, S.V * S.K.z));              \
        sS.w = fmaf(sS.w, S.W.w, fmaf(sa, S.Bb.w, S.V * S.K.w));              \
        float yv = fmaf(sa, S.C1, fmaf(S.V, S.C2, u));                        \
        if (col16 == 0) *py = yv;                                             \
        py += kD;                                                             \
      }

    for (int ph = 0; ph < kS / PHASE; ph++) {
      int base = (ph * PHASE) & (NSLOT - 1);
      LOADSLOT(base + 0, q0);
      LOADSLOT(base + 1, q1);
      LOADSLOT(base + 2, q2);
      LOADSLOT(base + 3, q3);
      #pragma unroll
      for (int s = 0; s < PHASE; s += 4) {
        STEP(q0); if (s + 4 < PHASE) LOADSLOT(base + s + 4, q0);
        STEP(q1); if (s + 5 < PHASE) LOADSLOT(base + s + 5, q1);
        STEP(q2); if (s + 6 < PHASE) LOADSLOT(base + s + 6, q2);
        STEP(q3); if (s + 7 < PHASE) LOADSLOT(base + s + 7, q3);
      }
      __syncthreads();
    }
    #undef LOADSLOT
    #undef STEP
    *(float4*)(s_out + srow) = sS;
  }
}

// ---------------- output: groupnorm(y)*lnx + c3*v, *gate → bf16 A for Wo -----
__global__ __launch_bounds__(256) void out_kernel(
    const float* __restrict__ y, const float* __restrict__ vA, const float* __restrict__ c3,
    const float* __restrict__ lnw, const float* __restrict__ lnb,
    const float* __restrict__ gate, ushort_t* __restrict__ Ay)
{
  int gid = blockIdx.x * 4 + (threadIdx.x >> 6);
  int lane = threadIdx.x & 63;
  int h = gid & (kH - 1);
  size_t off = (size_t)gid * kN + lane;
  float yv = y[off];
  float s = yv, s2 = yv * yv;
  #pragma unroll
  for (int o = 32; o > 0; o >>= 1) { s += __shfl_xor(s, o); s2 += __shfl_xor(s2, o); }
  float mean = s * (1.f / kN);
  float var = s2 * (1.f / kN) - mean * mean;
  float o1 = (yv - mean) * rsqrtf(var + 0.00064f);
  int d = h * kN + lane;
  float ov = o1 * lnw[d] + lnb[d];
  float rkv = c3[gid] * vA[off];
  Ay[off] = f2bf((ov + rkv) * gate[off]);
}

extern "C" void kernel_launch(void* const* d_in, const int* in_sizes, int n_in,
                              void* d_out, int out_size, void* d_ws, size_t ws_size,
                              hipStream_t stream)
{
  const float* x      = (const float*)d_in[0];
  const float* state1 = (const float*)d_in[1];
  const float* state2 = (const float*)d_in[2];
  const float* vfirst = (const float*)d_in[3];
  const float* ln1w   = (const float*)d_in[4];
  const float* ln1b   = (const float*)d_in[5];
  const float* xr_c   = (const float*)d_in[6];
  const float* xw_c   = (const float*)d_in[7];
  const float* xk_c   = (const float*)d_in[8];
  const float* xv_c   = (const float*)d_in[9];
  const float* xa_c   = (const float*)d_in[10];
  const float* xg_c   = (const float*)d_in[11];
  const float* Wr     = (const float*)d_in[12];
  const float* Wk     = (const float*)d_in[13];
  const float* Wv     = (const float*)d_in[14];
  const float* Wo     = (const float*)d_in[15];
  const float* w1     = (const float*)d_in[16];
  const float* w2     = (const float*)d_in[17];
  const float* w0     = (const float*)d_in[18];
  const float* a1     = (const float*)d_in[19];
  const float* a2     = (const float*)d_in[20];
  const float* a0     = (const float*)d_in[21];
  const float* g1     = (const float*)d_in[22];
  const float* g2     = (const float*)d_in[23];
  const float* v1     = (const float*)d_in[24];
  const float* v2     = (const float*)d_in[25];
  const float* v0     = (const float*)d_in[26];
  const float* k_k    = (const float*)d_in[27];
  const float* k_a    = (const float*)d_in[28];
  const float* r_k    = (const float*)d_in[29];
  const float* lnxw   = (const float*)d_in[30];
  const float* lnxb   = (const float*)d_in[31];

  float* out0  = (float*)d_out;
  float* s1out = out0 + (size_t)kS * kD;
  float* s2out = s1out + kD;

  size_t SD = (size_t)kS * kD;
  float* ws  = (float*)d_ws;
  float* xnB = ws;                 // bf16 xn + bf16 xprev; c12/c3 after gemm1
  float* rB  = ws + SD;
  float* kB  = ws + 2 * SD;
  float* vB  = ws + 3 * SD;
  float* wB  = ws + 4 * SD;
  float* aB  = ws + 5 * SD;
  float* kkB = ws + 6 * SD;
  float* bB  = ws + 7 * SD;
  float* gB  = ws + 8 * SD;
  float* yB  = ws + 9 * SD;

  ushort_t* xnbf    = (ushort_t*)xnB;
  ushort_t* xprevbf = (ushort_t*)xnB + SD;
  ushort_t* ArB = (ushort_t*)kkB;        // dead before post writes kkB
  ushort_t* AkB = (ushort_t*)kkB + SD;
  ushort_t* AvB = (ushort_t*)bB;         // bB first half
  ushort_t* B1  = (ushort_t*)bB + SD;    // bB second half: B1 | H | B2
  ushort_t* Hbuf = B1 + (size_t)320 * 4096;
  ushort_t* B2g  = Hbuf + (size_t)2048 * 320;
  ushort_t* B2a  = B2g + (size_t)2048 * 128;
  ushort_t* B2w  = B2a + (size_t)2048 * 64;
  ushort_t* B2v  = B2w + (size_t)2048 * 64;
  ushort_t* WrB = (ushort_t*)yB;         // dead before scan writes yB
  ushort_t* WkB = (ushort_t*)yB + SD;
  ushort_t* WvB = (ushort_t*)gB;         // dead before gemm2 writes gB
  ushort_t* AyB = (ushort_t*)aB;         // aB dead after post
  ushort_t* WoB = (ushort_t*)rB;         // rB (wr) dead after scan
  // c12/c3 live in the xn region (dead after gemm1, before post)
  float* c12B = xnB;                                   // stride-4 per gid
  float* c3B  = xnB + (size_t)kS * kH * 4;

  ln1_kernel<<<kS, 256, 0, stream>>>(x, ln1w, ln1b, xnbf, xprevbf, state1, s1out);
  mix3_cvt<<<kS, 256, 0, stream>>>(xnbf, xprevbf, xr_c, xk_c, xv_c, ArB, AkB, AvB);

  const int CVT_BLKS = (int)(SD / 4 / 256);
  {
    CvtArgs ca;
    ca.src[0] = Wr; ca.src[1] = Wk; ca.src[2] = Wv;
    ca.dst[0] = WrB; ca.dst[1] = WkB; ca.dst[2] = WvB;
    cvt_bf16_b<<<dim3(CVT_BLKS, 3), 256, 0, stream>>>(ca);
  }
  {
    PrepW1Args pa;
    pa.w1[0] = g1; pa.w1[1] = a1; pa.w1[2] = w1; pa.w1[3] = v1;
    pa.c[0] = xg_c; pa.c[1] = xa_c; pa.c[2] = xw_c; pa.c[3] = xv_c;
    pa.B1 = B1;
    prep_w1<<<dim3(64, 20), 256, 0, stream>>>(pa);
  }
  {
    PrepW2Args pa;
    pa.w2[0] = g2; pa.w2[1] = a2; pa.w2[2] = w2; pa.w2[3] = v2;
    pa.B2[0] = B2g; pa.B2[1] = B2a; pa.B2[2] = B2w; pa.B2[3] = B2v;
    pa.L[0] = 128; pa.L[1] = 64; pa.L[2] = 64; pa.L[3] = 32;
    prep_w2<<<dim3(32, 8, 4), 256, 0, stream>>>(pa);
  }
  {
    GemmArgs ga;
    ga.A[0] = ArB; ga.A[1] = AkB; ga.A[2] = AvB;
    ga.B[0] = WrB; ga.B[1] = WkB; ga.B[2] = WvB;
    ga.C[0] = rB;  ga.C[1] = kB;  ga.C[2] = vB;
    ga.resid[0] = nullptr; ga.resid[1] = nullptr; ga.resid[2] = nullptr;
    gemm_bf16_b<<<dim3(16, 16, 3), 256, 0, stream>>>(ga);
  }

  gemm1_kernel<<<dim3(5, 16), 256, 0, stream>>>(xnbf, xprevbf, B1, Hbuf);
  {
    Gemm2Args ga;
    ga.H = Hbuf;
    ga.B2[0] = B2g; ga.B2[1] = B2a; ga.B2[2] = B2w; ga.B2[3] = B2v;
    ga.Aofs[0] = 0; ga.Aofs[1] = 128; ga.Aofs[2] = 192; ga.Aofs[3] = 256;
    ga.L[0] = 128; ga.L[1] = 64; ga.L[2] = 64; ga.L[3] = 32;
    ga.bias[0] = nullptr; ga.bias[1] = a0; ga.bias[2] = w0; ga.bias[3] = v0;
    ga.out[0] = gB; ga.out[1] = aB; ga.out[2] = wB; ga.out[3] = vB;
    ga.vfirst = vfirst;
    gemm2_kernel<<<dim3(16, 16, 4), 256, 0, stream>>>(ga);
  }

  post_kernel<<<kS * kH / 4, 256, 0, stream>>>(kB, kkB, bB, aB, rB, wB,
                                               k_k, k_a, r_k, c12B, c3B);

  scan_kernel<<<kH * 8, 192, 0, stream>>>(state2, wB, rB, kB, vB, kkB, bB, c12B, yB, s2out);

  out_kernel<<<kS * kH / 4, 256, 0, stream>>>(yB, vB, c3B, lnxw, lnxb, gB, AyB);

  {
    CvtArgs ca;
    ca.src[0] = Wo; ca.src[1] = Wo; ca.src[2] = Wo;
    ca.dst[0] = WoB; ca.dst[1] = WoB; ca.dst[2] = WoB;
    cvt_bf16_b<<<dim3(CVT_BLKS, 1), 256, 0, stream>>>(ca);
  }
  {
    GemmArgs ga;
    ga.A[0] = AyB; ga.A[1] = AyB; ga.A[2] = AyB;
    ga.B[0] = WoB; ga.B[1] = WoB; ga.B[2] = WoB;
    ga.C[0] = out0; ga.C[1] = out0; ga.C[2] = out0;
    ga.resid[0] = x; ga.resid[1] = x; ga.resid[2] = x;
    gemm_bf16_b<<<dim3(16, 16, 1), 256, 0, stream>>>(ga);
  }
}